// Round 1
// baseline (40.816 us; speedup 1.0000x reference)
//
#include <hip/hip_runtime.h>

namespace {

template<int CTRL, int RM>
__device__ __forceinline__ float dpp_mov0(float v) {
  return __int_as_float(__builtin_amdgcn_update_dpp(
      0, __float_as_int(v), CTRL, RM, 0xF, false));
}
template<int CTRL, int RM>
__device__ __forceinline__ float dpp_mov1(float v) {
  return __int_as_float(__builtin_amdgcn_update_dpp(
      0x3f800000, __float_as_int(v), CTRL, RM, 0xF, false));
}

// inclusive 64-lane add scan (canonical GCN DPP sequence)
__device__ __forceinline__ float scan_add64(float v) {
  v += dpp_mov0<0x111, 0xF>(v);   // row_shr:1
  v += dpp_mov0<0x112, 0xF>(v);   // row_shr:2
  v += dpp_mov0<0x114, 0xF>(v);   // row_shr:4
  v += dpp_mov0<0x118, 0xF>(v);   // row_shr:8
  v += dpp_mov0<0x142, 0xA>(v);   // row_bcast15 -> rows 1,3
  v += dpp_mov0<0x143, 0xC>(v);   // row_bcast31 -> rows 2,3
  return v;
}

// inclusive 64-lane linear-recurrence scan: sigma_i = g_i*sigma_{i-1} + w_i
// segment compose: (G,W)_cur o (G,W)_prev = (G_cur*G_prev, W_cur + G_cur*W_prev)
template<int CTRL, int RM>
__device__ __forceinline__ void linrec_step(float& G, float& W) {
  float Wo = dpp_mov0<CTRL, RM>(W);  // missing/masked source -> 0
  float Go = dpp_mov1<CTRL, RM>(G);  // missing/masked source -> 1
  W = fmaf(G, Wo, W);
  G *= Go;
}
__device__ __forceinline__ float scan_linrec64(float g, float w) {
  float G = g, W = w;
  linrec_step<0x111, 0xF>(G, W);
  linrec_step<0x112, 0xF>(G, W);
  linrec_step<0x114, 0xF>(G, W);
  linrec_step<0x118, 0xF>(G, W);
  linrec_step<0x142, 0xA>(G, W);
  linrec_step<0x143, 0xC>(G, W);
  return W;
}

// lhs = I - 0.5*dt*A is diag(d_n) + h*r_i*r_k (k<i), rank-1 strictly-lower.
struct Coef {
  float r, inv_d, g, hr, tmd;  // tmd = 2 - d_n
};

__device__ __forceinline__ Coef make_coef(float dt, int n) {
  Coef c;
  float h = 0.5f * dt;
  float fn = (float)n;
  c.r = sqrtf(2.f * fn + 1.f);
  float dc = 1.f + h * (fn + 1.f);
  c.inv_d = 1.f / dc;
  c.g = (1.f - h * fn) / dc;      // = 1 - h*r^2/d
  c.hr = h * c.r;
  c.tmd = 2.f - dc;
  return c;
}

// y = lhs^{-1} z via O(N) forward substitution:
//   y_i = (z_i - h r_i sig_{i-1})/d_i,  sig_i = g_i sig_{i-1} + r_i z_i / d_i
__device__ __forceinline__ float lhs_solve(float z, const Coef& c, int lane) {
  float W = scan_linrec64(c.g, c.r * z * c.inv_d);
  float sp = __shfl_up(W, 1, 64);
  if (lane == 0) sp = 0.f;
  return (z - c.hr * sp) * c.inv_d;
}

// y = A_bar x = lhs^{-1} (2I - lhs) x
__device__ __forceinline__ float abar_apply(float x, const Coef& c, int lane) {
  float t = c.r * x;
  float S = scan_add64(t);
  float Sp = S - t;                        // exclusive prefix sum of r_k x_k
  float z = c.tmd * x - c.hr * Sp;         // (2I - lhs) x
  return lhs_solve(z, c, lane);
}

__device__ __forceinline__ float softplus_dt(float ldt) {
  return log1pf(expf(ldt)) + 1e-6f;
}

} // namespace

// Kernel 1: PT[m][k] = P[k][m], P = A_bar^64. Block m runs the chain on e_m.
__global__ __launch_bounds__(64) void hippo_pow64(const float* __restrict__ ldt_p,
                                                  float* __restrict__ PT) {
  const int lane = threadIdx.x;
  const int m = blockIdx.x;
  const float dt = softplus_dt(ldt_p[0]);
  const Coef c = make_coef(dt, lane);
  float x = (lane == m) ? 1.f : 0.f;
  for (int s = 0; s < 64; ++s) x = abar_apply(x, c, lane);
  PT[m * 64 + lane] = x;   // coalesced
}

// Kernel 2: per d, wave0 builds V (64 applies), wave1 builds U (31 dense P^T
// matvecs), all 4 waves do the 32x64 dot-product epilogue.
__global__ __launch_bounds__(256) void hippo_main(
    const float* __restrict__ B, const float* __restrict__ C,
    const float* __restrict__ Dv, const float* __restrict__ ldt_p,
    const float* __restrict__ PT, float* __restrict__ out, int NI, int L) {
  __shared__ __align__(16) float Vl[64 * 65];  // pad 65 -> conflict-free both ways
  __shared__ __align__(16) float Ul[32 * 64];
  const int d = blockIdx.x;
  const int tau = threadIdx.x;
  const int lane = tau & 63;
  const int w = tau >> 6;
  const float dt = softplus_dt(ldt_p[0]);
  const Coef c = make_coef(dt, lane);

  if (w == 0) {
    // B_bar[d] = lhs^{-1} (dt * B[d]); then v_{j+1} = A_bar v_j
    float b = B[d * 64 + lane];
    float v = lhs_solve(dt * b, c, lane);
    for (int j = 0; j < 64; ++j) {
      Vl[j * 65 + lane] = v;
      if (j < 63) v = abar_apply(v, c, lane);
    }
  } else if (w == 1) {
    // u_{i+1}[n] = sum_k P[k][n] u_i[k]; lane n holds column n of P in regs.
    float pc[64];
    const float4* pt4 = (const float4*)(PT + lane * 64);
    #pragma unroll
    for (int q = 0; q < 16; ++q) {
      float4 f = pt4[q];
      pc[4*q+0] = f.x; pc[4*q+1] = f.y; pc[4*q+2] = f.z; pc[4*q+3] = f.w;
    }
    float u = C[d * 64 + lane];
    for (int i = 0; i < NI; ++i) {
      Ul[i * 64 + lane] = u;
      if (i < NI - 1) {
        float a0 = 0.f, a1 = 0.f, a2 = 0.f, a3 = 0.f;
        #pragma unroll
        for (int k = 0; k < 64; k += 4) {
          float u0 = __int_as_float(__builtin_amdgcn_readlane(__float_as_int(u), k + 0));
          float u1 = __int_as_float(__builtin_amdgcn_readlane(__float_as_int(u), k + 1));
          float u2 = __int_as_float(__builtin_amdgcn_readlane(__float_as_int(u), k + 2));
          float u3 = __int_as_float(__builtin_amdgcn_readlane(__float_as_int(u), k + 3));
          a0 = fmaf(pc[k+0], u0, a0);
          a1 = fmaf(pc[k+1], u1, a1);
          a2 = fmaf(pc[k+2], u2, a2);
          a3 = fmaf(pc[k+3], u3, a3);
        }
        u = (a0 + a1) + (a2 + a3);
      }
    }
  }
  __syncthreads();

  // Epilogue: K[d, i*64+j] = dot(U[i], V[j]); thread -> j=lane, i = w + 4k.
  const int j = lane;
  float vr[64];
  #pragma unroll
  for (int n = 0; n < 64; ++n) vr[n] = Vl[j * 65 + n];   // (j+n)%32 banks: free
  for (int i = w; i < NI; i += 4) {
    const float4* u4 = (const float4*)(Ul + i * 64);     // wave-uniform: broadcast
    float a0 = 0.f, a1 = 0.f, a2 = 0.f, a3 = 0.f;
    #pragma unroll
    for (int q = 0; q < 16; ++q) {
      float4 f = u4[q];
      a0 = fmaf(vr[4*q+0], f.x, a0);
      a1 = fmaf(vr[4*q+1], f.y, a1);
      a2 = fmaf(vr[4*q+2], f.z, a2);
      a3 = fmaf(vr[4*q+3], f.w, a3);
    }
    float y = (a0 + a1) + (a2 + a3);
    if ((i | j) == 0) y += Dv[d];
    out[(size_t)d * L + i * 64 + j] = y;   // lanes contiguous: coalesced
  }
}

extern "C" void kernel_launch(void* const* d_in, const int* in_sizes, int n_in,
                              void* d_out, int out_size, void* d_ws, size_t ws_size,
                              hipStream_t stream) {
  const float* B   = (const float*)d_in[0];
  const float* C   = (const float*)d_in[1];
  const float* Dv  = (const float*)d_in[2];
  const float* ldt = (const float*)d_in[3];
  // d_in[4] is L as a device scalar; derive L host-side instead:
  const int d_model = in_sizes[2];        // 1024 (size of D vector)
  const int L = out_size / d_model;       // 2048
  const int NI = L / 64;                  // 32 chunks of 64
  float* PT = (float*)d_ws;               // 64*64 floats = 16 KiB scratch
  hippo_pow64<<<64, 64, 0, stream>>>(ldt, PT);
  hippo_main<<<d_model, 256, 0, stream>>>(B, C, Dv, ldt, PT, (float*)d_out, NI, L);
}